// Round 14
// baseline (1299.330 us; speedup 1.0000x reference)
//
#include <hip/hip_runtime.h>
#include <hip/hip_bf16.h>
#include <math.h>

typedef __attribute__((ext_vector_type(8))) short short8;
typedef __attribute__((ext_vector_type(4))) float f32x4;

__device__ __forceinline__ unsigned short f2bf(float f){
  union { __hip_bfloat16 h; unsigned short u; } cv;
  cv.h = __float2bfloat16(f);
  return cv.u;
}

__device__ __forceinline__ float bf2f(unsigned short u){
  union { unsigned int i; float f; } v;
  v.i = ((unsigned int)u) << 16;
  return v.f;
}

// gelu via sigmoid: 0.5v(1+tanh(u)) == v*sigmoid(2u), exp2-folded constants
__device__ __forceinline__ float gelu_f(float v){
  float v2 = v * v;
  float nw = v * fmaf(-0.10294364f, v2, -2.3022090f);  // -2u*log2(e)
  float e  = __builtin_amdgcn_exp2f(nw);
  return v * __builtin_amdgcn_rcpf(1.f + e);
}

__device__ __forceinline__ void gload_lds16(const unsigned short* g, unsigned short* l){
  __builtin_amdgcn_global_load_lds(
      (const __attribute__((address_space(1))) void*)g,
      (__attribute__((address_space(3))) void*)l, 16, 0, 0);
}

// ---------------- all four weight transposes in one launch -------------------
__global__ __launch_bounds__(256) void wconv4(
    const float* __restrict__ qkv_w, const float* __restrict__ proj_w,
    const float* __restrict__ fc1_w, const float* __restrict__ fc2_w,
    unsigned short* __restrict__ wq, unsigned short* __restrict__ wp,
    unsigned short* __restrict__ w1, unsigned short* __restrict__ w2){
  int idx = blockIdx.x * 256 + threadIdx.x;
  if (idx < 196608){                       // qkv: K=256 N=768
    int k = idx / 768, n = idx % 768;
    wq[n*256 + k] = f2bf(qkv_w[idx]);
  } else if (idx < 262144){                // proj: K=256 N=256
    int l = idx - 196608;
    int k = l >> 8, n = l & 255;
    wp[n*256 + k] = f2bf(proj_w[l]);
  } else if (idx < 524288){                // fc1: K=256 N=1024
    int l = idx - 262144;
    int k = l >> 10, n = l & 1023;
    w1[n*256 + k] = f2bf(fc1_w[l]);
  } else {                                 // fc2: K=1024 N=256
    int l = idx - 524288;
    int k = l >> 8, n = l & 255;
    w2[n*1024 + k] = f2bf(fc2_w[l]);
  }
}

// ---------------- LayerNorm: x f32 [M][256] -> out bf16 [M][256] -------------
__global__ __launch_bounds__(256) void ln_kernel(
    const float* __restrict__ x, const float* __restrict__ g,
    const float* __restrict__ b, unsigned short* __restrict__ out){
  const int lane = threadIdx.x & 63;
  const int wv = threadIdx.x >> 6;
  const long row = (long)blockIdx.x * 4 + wv;
  const float4 xv = ((const float4*)(x + row * 256))[lane];
  float s  = xv.x + xv.y + xv.z + xv.w;
  float s2 = xv.x*xv.x + xv.y*xv.y + xv.z*xv.z + xv.w*xv.w;
  #pragma unroll
  for (int m = 1; m < 64; m <<= 1){
    s  += __shfl_xor(s,  m);
    s2 += __shfl_xor(s2, m);
  }
  float mu = s * (1.f/256.f);
  float rs = rsqrtf(s2 * (1.f/256.f) - mu*mu + 1e-5f);
  float4 gv = ((const float4*)g)[lane];
  float4 bv = ((const float4*)b)[lane];
  ushort4 o;
  o.x = f2bf((xv.x - mu)*rs*gv.x + bv.x);
  o.y = f2bf((xv.y - mu)*rs*gv.y + bv.y);
  o.z = f2bf((xv.z - mu)*rs*gv.z + bv.z);
  o.w = f2bf((xv.w - mu)*rs*gv.w + bv.w);
  ((ushort4*)(out + row * 256))[lane] = o;
}

// ---------------- GEMM: A[M][K] bf16 @ Wt[N][K] bf16 -> out [M][N] -----------
// SWAPPED MFMA: per lane row = ..+l15, cols = ..+4*l4+{0..3}
template<int MODE>
__global__ __launch_bounds__(256, 4) void gemm_bt(
    const unsigned short* __restrict__ A,
    const unsigned short* __restrict__ Bt,
    const float* __restrict__ bias,
    const unsigned short* __restrict__ res,
    void* __restrict__ out,
    int N, int K, int nbx){
  __shared__ unsigned short S[2*128*64];
  unsigned short* As = S;
  unsigned short* Bs = S + 128*64;
  const int tid  = threadIdx.x;
  const int lane = tid & 63;
  const int wave = tid >> 6;
  const int wm = wave >> 1, wn = wave & 1;

  const int nby  = gridDim.x / nbx;
  const int bid  = blockIdx.x;
  const int xcd  = bid & 7;
  const int local = bid >> 3;
  const int lrow = local / nbx;
  const int rowb = xcd * (nby >> 3) + lrow;
  const int colb = local - lrow * nbx;
  const long row0 = (long)rowb * 128;
  const int  col0 = colb * 128;
  const int l15 = lane & 15, l4 = lane >> 4;

  f32x4 acc[4][4];
  #pragma unroll
  for (int i = 0; i < 4; ++i)
    #pragma unroll
    for (int j = 0; j < 4; ++j)
      acc[i][j] = (f32x4){0.f, 0.f, 0.f, 0.f};

  const int nk = K >> 6;
  for (int kt = 0; kt < nk; ++kt){
    #pragma unroll
    for (int it = 0; it < 4; ++it){
      int ch = it*256 + tid;
      int r = ch >> 3, cc = ch & 7;
      int srcc = ((cc ^ (r & 7)) << 3);
      gload_lds16(A  + (row0 + r) * K + kt*64 + srcc, &As[ch*8]);
      gload_lds16(Bt + (long)(col0 + r) * K + kt*64 + srcc, &Bs[ch*8]);
    }
    __syncthreads();
    #pragma unroll
    for (int ks = 0; ks < 2; ++ks){
      short8 af[4], bfr[4];
      #pragma unroll
      for (int mi = 0; mi < 4; ++mi){
        int ar = wm*64 + mi*16 + l15;
        af[mi] = *(const short8*)&As[ar*64 + (((ks*4 + l4) ^ (ar & 7)) << 3)];
      }
      #pragma unroll
      for (int ni = 0; ni < 4; ++ni){
        int br = wn*64 + ni*16 + l15;
        bfr[ni] = *(const short8*)&Bs[br*64 + (((ks*4 + l4) ^ (br & 7)) << 3)];
      }
      #pragma unroll
      for (int mi = 0; mi < 4; ++mi)
        #pragma unroll
        for (int ni = 0; ni < 4; ++ni)
          acc[mi][ni] = __builtin_amdgcn_mfma_f32_16x16x32_bf16(bfr[ni], af[mi], acc[mi][ni], 0, 0, 0);
    }
    __syncthreads();
  }

  if (MODE == 2){
    float* outf = (float*)out;
    #pragma unroll
    for (int mi = 0; mi < 4; ++mi){
      long row = row0 + wm*64 + mi*16 + l15;
      #pragma unroll
      for (int ni = 0; ni < 4; ++ni){
        int colg = col0 + wn*64 + ni*16 + 4*l4;
        float4 bv = *(const float4*)&bias[colg];
        long idx = row * N + colg;
        ushort4 rv = *(const ushort4*)&res[idx];
        float4 o;
        o.x = acc[mi][ni][0] + bv.x + bf2f(rv.x);
        o.y = acc[mi][ni][1] + bv.y + bf2f(rv.y);
        o.z = acc[mi][ni][2] + bv.z + bf2f(rv.z);
        o.w = acc[mi][ni][3] + bv.w + bf2f(rv.w);
        *(float4*)&outf[idx] = o;
      }
    }
  } else {
    unsigned short* outp = (unsigned short*)out;
    #pragma unroll
    for (int mi = 0; mi < 4; ++mi){
      long row = row0 + wm*64 + mi*16 + l15;
      #pragma unroll
      for (int ni = 0; ni < 4; ++ni){
        int colg = col0 + wn*64 + ni*16 + 4*l4;
        float4 bv = *(const float4*)&bias[colg];
        float v0 = acc[mi][ni][0] + bv.x;
        float v1 = acc[mi][ni][1] + bv.y;
        float v2 = acc[mi][ni][2] + bv.z;
        float v3 = acc[mi][ni][3] + bv.w;
        if (MODE == 1){ v0 = gelu_f(v0); v1 = gelu_f(v1); v2 = gelu_f(v2); v3 = gelu_f(v3); }
        uint2 dv;
        dv.x = ((unsigned int)f2bf(v1) << 16) | f2bf(v0);
        dv.y = ((unsigned int)f2bf(v3) << 16) | f2bf(v2);
        *(uint2*)&outp[row * N + colg] = dv;
      }
    }
  }
}

// ---------------- Window attention: one WAVE = one (window, head) ------------
__global__ __launch_bounds__(64, 3) void attn_kernel(
    const unsigned short* __restrict__ qkv,
    const float* __restrict__ bt,
    unsigned short* __restrict__ ao){
  __shared__ unsigned short P[64*64];
  const int lane = threadIdx.x;
  const int wb = blockIdx.x;
  const int w = wb >> 3, h = wb & 7;
  const int bidx = w >> 10, rem = w & 1023;
  const int wy = rem >> 5, wx = rem & 31;
  const long tok0 = (long)bidx * 65536 + (long)wy * 2048 + wx * 8;
  const int l15 = lane & 15, l4 = lane >> 4;

  short8 qf[4], kf[4];
  #pragma unroll
  for (int t = 0; t < 4; ++t){
    int n = t*16 + l15;
    long tok = tok0 + (n >> 3) * 256 + (n & 7);
    qf[t] = *(const short8*)(qkv + tok*768 +       h*32 + 8*l4);
    kf[t] = *(const short8*)(qkv + tok*768 + 256 + h*32 + 8*l4);
  }
  f32x4 s[4][4];
  #pragma unroll
  for (int i = 0; i < 4; ++i)
    #pragma unroll
    for (int j = 0; j < 4; ++j)
      s[i][j] = (f32x4){0.f, 0.f, 0.f, 0.f};
  #pragma unroll
  for (int mi = 0; mi < 4; ++mi)
    #pragma unroll
    for (int ni = 0; ni < 4; ++ni)
      s[mi][ni] = __builtin_amdgcn_mfma_f32_16x16x32_bf16(qf[mi], kf[ni], s[mi][ni], 0, 0, 0);

  const float scale = 0.17677669529663687f; // 1/sqrt(32)
  #pragma unroll
  for (int mi = 0; mi < 4; ++mi){
    #pragma unroll
    for (int j = 0; j < 4; ++j){
      int n = mi*16 + 4*l4 + j;
      int ny = n >> 3, nx = n & 7;
      #pragma unroll
      for (int ni = 0; ni < 4; ++ni){
        int m = ni*16 + l15;
        int db = (ny - (m >> 3) + 7) * 15 + (nx - (m & 7) + 7);
        s[mi][ni][j] = s[mi][ni][j] * scale + bt[db*8 + h];
      }
    }
  }
  #pragma unroll
  for (int mi = 0; mi < 4; ++mi){
    #pragma unroll
    for (int j = 0; j < 4; ++j){
      float mx = fmaxf(fmaxf(s[mi][0][j], s[mi][1][j]), fmaxf(s[mi][2][j], s[mi][3][j]));
      mx = fmaxf(mx, __shfl_xor(mx, 1));
      mx = fmaxf(mx, __shfl_xor(mx, 2));
      mx = fmaxf(mx, __shfl_xor(mx, 4));
      mx = fmaxf(mx, __shfl_xor(mx, 8));
      float sm = 0.f;
      #pragma unroll
      for (int ni = 0; ni < 4; ++ni){
        float p = __expf(s[mi][ni][j] - mx);
        s[mi][ni][j] = p;
        sm += p;
      }
      sm += __shfl_xor(sm, 1);
      sm += __shfl_xor(sm, 2);
      sm += __shfl_xor(sm, 4);
      sm += __shfl_xor(sm, 8);
      float inv = __builtin_amdgcn_rcpf(sm);
      int n = mi*16 + 4*l4 + j;
      int swz = (n & 7) << 3;
      #pragma unroll
      for (int ni = 0; ni < 4; ++ni){
        int m = ni*16 + l15;
        P[n*64 + (m ^ swz)] = f2bf(s[mi][ni][j] * inv);
      }
    }
  }
  // no barrier needed: P written and read by this wave only

  f32x4 o[4][2];
  #pragma unroll
  for (int i = 0; i < 4; ++i)
    #pragma unroll
    for (int j = 0; j < 2; ++j)
      o[i][j] = (f32x4){0.f, 0.f, 0.f, 0.f};
  #pragma unroll
  for (int kt = 0; kt < 2; ++kt){
    short8 vf[2];
    #pragma unroll
    for (int ni = 0; ni < 2; ++ni){
      union { unsigned short u[8]; short8 v; } tmp;
      #pragma unroll
      for (int i = 0; i < 8; ++i){
        int kk = kt*32 + 8*l4 + i;
        long tok = tok0 + (kk >> 3) * 256 + (kk & 7);
        tmp.u[i] = qkv[tok*768 + 512 + h*32 + ni*16 + l15];
      }
      vf[ni] = tmp.v;
    }
    #pragma unroll
    for (int mi = 0; mi < 4; ++mi){
      int r = mi*16 + l15;
      short8 pf = *(const short8*)&P[r*64 + ((kt*32 + 8*l4) ^ ((r & 7) << 3))];
      #pragma unroll
      for (int ni = 0; ni < 2; ++ni)
        o[mi][ni] = __builtin_amdgcn_mfma_f32_16x16x32_bf16(pf, vf[ni], o[mi][ni], 0, 0, 0);
    }
  }
  #pragma unroll
  for (int mi = 0; mi < 4; ++mi){
    #pragma unroll
    for (int j = 0; j < 4; ++j){
      int n = mi*16 + 4*l4 + j;
      long tok = tok0 + (n >> 3) * 256 + (n & 7);
      #pragma unroll
      for (int ni = 0; ni < 2; ++ni)
        ao[tok*256 + h*32 + ni*16 + l15] = f2bf(o[mi][ni][j]);
    }
  }
}

// ---------------- proj + residual + LN2 fused (swapped MFMA, packed stores) ---
// writes h (bf16) and hn (bf16); LN2 stats computed on exact f32 values
__global__ __launch_bounds__(512, 4) void proj_ln2(
    const unsigned short* __restrict__ A,
    const unsigned short* __restrict__ Bt,
    const float* __restrict__ bias,
    const float* __restrict__ res,
    const float* __restrict__ g2,
    const float* __restrict__ b2,
    unsigned short* __restrict__ hout,
    unsigned short* __restrict__ hn){
  __shared__ unsigned short As[128*64];
  __shared__ unsigned short Bs[256*64];
  __shared__ float redsum[4][128];
  __shared__ float redsq[4][128];
  __shared__ float mu_s[128];
  __shared__ float rs_s[128];
  const int tid = threadIdx.x, lane = tid & 63, wave = tid >> 6;
  const int l15 = lane & 15, l4 = lane >> 4;
  const int wm = wave >> 2, wn = wave & 3;
  const long row0 = (long)blockIdx.x * 128;

  f32x4 acc[4][4];
  #pragma unroll
  for (int i = 0; i < 4; ++i)
    #pragma unroll
    for (int j = 0; j < 4; ++j)
      acc[i][j] = (f32x4){0.f, 0.f, 0.f, 0.f};

  for (int kt = 0; kt < 4; ++kt){
    #pragma unroll
    for (int it = 0; it < 2; ++it){
      int ch = it*512 + tid;
      int r = ch >> 3, cc = ch & 7;
      gload_lds16(A + (row0 + r)*256 + kt*64 + ((cc ^ (r & 7))*8), &As[ch*8]);
    }
    #pragma unroll
    for (int it = 0; it < 4; ++it){
      int ch = it*512 + tid;
      int r = ch >> 3, cc = ch & 7;
      gload_lds16(Bt + r*256 + kt*64 + ((cc ^ (r & 7))*8), &Bs[ch*8]);
    }
    __syncthreads();
    #pragma unroll
    for (int ks = 0; ks < 2; ++ks){
      short8 af[4], bf[4];
      #pragma unroll
      for (int mi = 0; mi < 4; ++mi){
        int ar = wm*64 + mi*16 + l15;
        af[mi] = *(const short8*)&As[ar*64 + (((ks*4 + l4) ^ (ar & 7))*8)];
      }
      #pragma unroll
      for (int ni = 0; ni < 4; ++ni){
        int br = wn*64 + ni*16 + l15;
        bf[ni] = *(const short8*)&Bs[br*64 + (((ks*4 + l4) ^ (br & 7))*8)];
      }
      #pragma unroll
      for (int mi = 0; mi < 4; ++mi)
        #pragma unroll
        for (int ni = 0; ni < 4; ++ni)
          acc[mi][ni] = __builtin_amdgcn_mfma_f32_16x16x32_bf16(bf[ni], af[mi], acc[mi][ni], 0, 0, 0);
    }
    __syncthreads();
  }

  // pass 1: v = acc + bias + res; packed hh writes; per-row stats
  float psum[4], psq[4];
  #pragma unroll
  for (int mi = 0; mi < 4; ++mi){ psum[mi] = 0.f; psq[mi] = 0.f; }
  #pragma unroll
  for (int mi = 0; mi < 4; ++mi){
    long row = row0 + wm*64 + mi*16 + l15;
    #pragma unroll
    for (int ni = 0; ni < 4; ++ni){
      int col = wn*64 + ni*16 + 4*l4;
      float4 bv = *(const float4*)&bias[col];
      long idx = row * 256 + col;
      float4 rv = *(const float4*)&res[idx];
      float v0 = acc[mi][ni][0] + bv.x + rv.x;
      float v1 = acc[mi][ni][1] + bv.y + rv.y;
      float v2 = acc[mi][ni][2] + bv.z + rv.z;
      float v3 = acc[mi][ni][3] + bv.w + rv.w;
      acc[mi][ni][0] = v0; acc[mi][ni][1] = v1;
      acc[mi][ni][2] = v2; acc[mi][ni][3] = v3;
      uint2 dv;
      dv.x = ((unsigned int)f2bf(v1) << 16) | f2bf(v0);
      dv.y = ((unsigned int)f2bf(v3) << 16) | f2bf(v2);
      *(uint2*)&hout[idx] = dv;
      psum[mi] += v0 + v1 + v2 + v3;
      psq[mi]  += v0*v0 + v1*v1 + v2*v2 + v3*v3;
    }
  }
  #pragma unroll
  for (int mi = 0; mi < 4; ++mi){
    float s = psum[mi], q = psq[mi];
    s += __shfl_xor(s, 16); q += __shfl_xor(q, 16);
    s += __shfl_xor(s, 32); q += __shfl_xor(q, 32);
    if (l4 == 0){
      int rl = wm*64 + mi*16 + l15;
      redsum[wn][rl] = s;
      redsq[wn][rl]  = q;
    }
  }
  __syncthreads();
  if (tid < 128){
    float s = redsum[0][tid] + redsum[1][tid] + redsum[2][tid] + redsum[3][tid];
    float q = redsq[0][tid]  + redsq[1][tid]  + redsq[2][tid]  + redsq[3][tid];
    float mu = s * (1.f/256.f);
    mu_s[tid] = mu;
    rs_s[tid] = rsqrtf(q * (1.f/256.f) - mu*mu + 1e-5f);
  }
  __syncthreads();
  // pass 2: hn = (v - mu)*rs*g2 + b2, packed
  #pragma unroll
  for (int mi = 0; mi < 4; ++mi){
    int rl = wm*64 + mi*16 + l15;
    float mu = mu_s[rl], rs = rs_s[rl];
    long row = row0 + rl;
    #pragma unroll
    for (int ni = 0; ni < 4; ++ni){
      int col = wn*64 + ni*16 + 4*l4;
      float4 gv = *(const float4*)&g2[col];
      float4 bv = *(const float4*)&b2[col];
      uint2 dv;
      dv.x = ((unsigned int)f2bf((acc[mi][ni][1]-mu)*rs*gv.y + bv.y) << 16)
           |  (unsigned int)f2bf((acc[mi][ni][0]-mu)*rs*gv.x + bv.x);
      dv.y = ((unsigned int)f2bf((acc[mi][ni][3]-mu)*rs*gv.w + bv.w) << 16)
           |  (unsigned int)f2bf((acc[mi][ni][2]-mu)*rs*gv.z + bv.z);
      *(uint2*)&hn[row*256 + col] = dv;
    }
  }
}

extern "C" void kernel_launch(void* const* d_in, const int* in_sizes, int n_in,
                              void* d_out, int out_size, void* d_ws, size_t ws_size,
                              hipStream_t stream){
  const float* x      = (const float*)d_in[0];
  const float* ln1_g  = (const float*)d_in[1];
  const float* ln1_b  = (const float*)d_in[2];
  const float* qkv_w  = (const float*)d_in[3];
  const float* qkv_b  = (const float*)d_in[4];
  const float* proj_w = (const float*)d_in[5];
  const float* proj_b = (const float*)d_in[6];
  const float* btab   = (const float*)d_in[7];
  const float* ln2_g  = (const float*)d_in[8];
  const float* ln2_b  = (const float*)d_in[9];
  const float* fc1_w  = (const float*)d_in[10];
  const float* fc1_b  = (const float*)d_in[11];
  const float* fc2_w  = (const float*)d_in[12];
  const float* fc2_b  = (const float*)d_in[13];

  const long M = (long)in_sizes[0] / 256;  // 262144 tokens

  char* ws = (char*)d_ws;
  unsigned short* xn  = (unsigned short*)(ws);
  unsigned short* ao  = xn;
  unsigned short* act = xn;
  unsigned short* qkv = (unsigned short*)(ws + 134217728);
  unsigned short* hn  = (unsigned short*)(ws + 536870912);
  unsigned short* wq  = (unsigned short*)(ws + 671088640);
  unsigned short* wp  = wq + 256*768;
  unsigned short* w1  = wp + 256*256;
  unsigned short* w2  = w1 + 256*1024;
  unsigned short* hh  = (unsigned short*)(ws + (712ull << 20));
  float* outf = (float*)d_out;

  // all 4 weight transposes in one launch (786432 elems)
  wconv4<<<3072, 256, 0, stream>>>(qkv_w, proj_w, fc1_w, fc2_w, wq, wp, w1, w2);

  // LN1
  ln_kernel<<<M/4, 256, 0, stream>>>(x, ln1_g, ln1_b, xn);
  // QKV (swizzled): nbx=6
  gemm_bt<0><<<6 * (M/128), 256, 0, stream>>>(xn, wq, qkv_b, nullptr, qkv, 768, 256, 6);
  // window attention: one wave per (window, head)
  attn_kernel<<<(M/64) * 8, 64, 0, stream>>>(qkv, btab, ao);
  // proj + residual + LN2  (h bf16 -> hh, hn bf16)
  proj_ln2<<<M/128, 512, 0, stream>>>(ao, wp, proj_b, x, ln2_g, ln2_b, hh, hn);
  // FC1 + GELU (swizzled): nbx=8
  gemm_bt<1><<<8 * (M/128), 256, 0, stream>>>(hn, w1, fc1_b, nullptr, act, 1024, 256, 8);
  // FC2 + residual(h bf16) -> out f32 (swizzled): nbx=2
  gemm_bt<2><<<2 * (M/128), 256, 0, stream>>>(act, w2, fc2_b, hh, outf, 256, 1024, 2);
}

// Round 15
// 1250.356 us; speedup vs baseline: 1.0392x; 1.0392x over previous
//
#include <hip/hip_runtime.h>
#include <hip/hip_bf16.h>
#include <math.h>

typedef __attribute__((ext_vector_type(8))) short short8;
typedef __attribute__((ext_vector_type(4))) float f32x4;

__device__ __forceinline__ unsigned short f2bf(float f){
  union { __hip_bfloat16 h; unsigned short u; } cv;
  cv.h = __float2bfloat16(f);
  return cv.u;
}

__device__ __forceinline__ float bf2f(unsigned short u){
  union { unsigned int i; float f; } v;
  v.i = ((unsigned int)u) << 16;
  return v.f;
}

// gelu via sigmoid: 0.5v(1+tanh(u)) == v*sigmoid(2u), exp2-folded constants
__device__ __forceinline__ float gelu_f(float v){
  float v2 = v * v;
  float nw = v * fmaf(-0.10294364f, v2, -2.3022090f);  // -2u*log2(e)
  float e  = __builtin_amdgcn_exp2f(nw);
  return v * __builtin_amdgcn_rcpf(1.f + e);
}

__device__ __forceinline__ void gload_lds16(const unsigned short* g, unsigned short* l){
  __builtin_amdgcn_global_load_lds(
      (const __attribute__((address_space(1))) void*)g,
      (__attribute__((address_space(3))) void*)l, 16, 0, 0);
}

// ---------------- all four weight transposes in one launch -------------------
__global__ __launch_bounds__(256) void wconv4(
    const float* __restrict__ qkv_w, const float* __restrict__ proj_w,
    const float* __restrict__ fc1_w, const float* __restrict__ fc2_w,
    unsigned short* __restrict__ wq, unsigned short* __restrict__ wp,
    unsigned short* __restrict__ w1, unsigned short* __restrict__ w2){
  int idx = blockIdx.x * 256 + threadIdx.x;
  if (idx < 196608){                       // qkv: K=256 N=768
    int k = idx / 768, n = idx % 768;
    wq[n*256 + k] = f2bf(qkv_w[idx]);
  } else if (idx < 262144){                // proj: K=256 N=256
    int l = idx - 196608;
    int k = l >> 8, n = l & 255;
    wp[n*256 + k] = f2bf(proj_w[l]);
  } else if (idx < 524288){                // fc1: K=256 N=1024
    int l = idx - 262144;
    int k = l >> 10, n = l & 1023;
    w1[n*256 + k] = f2bf(fc1_w[l]);
  } else {                                 // fc2: K=1024 N=256
    int l = idx - 524288;
    int k = l >> 8, n = l & 255;
    w2[n*1024 + k] = f2bf(fc2_w[l]);
  }
}

// ---------------- LayerNorm: x f32 [M][256] -> out bf16 [M][256] -------------
__global__ __launch_bounds__(256) void ln_kernel(
    const float* __restrict__ x, const float* __restrict__ g,
    const float* __restrict__ b, unsigned short* __restrict__ out){
  const int lane = threadIdx.x & 63;
  const int wv = threadIdx.x >> 6;
  const long row = (long)blockIdx.x * 4 + wv;
  const float4 xv = ((const float4*)(x + row * 256))[lane];
  float s  = xv.x + xv.y + xv.z + xv.w;
  float s2 = xv.x*xv.x + xv.y*xv.y + xv.z*xv.z + xv.w*xv.w;
  #pragma unroll
  for (int m = 1; m < 64; m <<= 1){
    s  += __shfl_xor(s,  m);
    s2 += __shfl_xor(s2, m);
  }
  float mu = s * (1.f/256.f);
  float rs = rsqrtf(s2 * (1.f/256.f) - mu*mu + 1e-5f);
  float4 gv = ((const float4*)g)[lane];
  float4 bv = ((const float4*)b)[lane];
  ushort4 o;
  o.x = f2bf((xv.x - mu)*rs*gv.x + bv.x);
  o.y = f2bf((xv.y - mu)*rs*gv.y + bv.y);
  o.z = f2bf((xv.z - mu)*rs*gv.z + bv.z);
  o.w = f2bf((xv.w - mu)*rs*gv.w + bv.w);
  ((ushort4*)(out + row * 256))[lane] = o;
}

// ---------------- GEMM: A[M][K] bf16 @ Wt[N][K] bf16 -> out [M][N] -----------
// SWAPPED MFMA: per lane row = ..+l15, cols = ..+4*l4+{0..3}
template<int MODE>
__global__ __launch_bounds__(256, 4) void gemm_bt(
    const unsigned short* __restrict__ A,
    const unsigned short* __restrict__ Bt,
    const float* __restrict__ bias,
    const unsigned short* __restrict__ res,
    void* __restrict__ out,
    int N, int K, int nbx){
  __shared__ unsigned short S[2*128*64];
  unsigned short* As = S;
  unsigned short* Bs = S + 128*64;
  const int tid  = threadIdx.x;
  const int lane = tid & 63;
  const int wave = tid >> 6;
  const int wm = wave >> 1, wn = wave & 1;

  const int nby  = gridDim.x / nbx;
  const int bid  = blockIdx.x;
  const int xcd  = bid & 7;
  const int local = bid >> 3;
  const int lrow = local / nbx;
  const int rowb = xcd * (nby >> 3) + lrow;
  const int colb = local - lrow * nbx;
  const long row0 = (long)rowb * 128;
  const int  col0 = colb * 128;
  const int l15 = lane & 15, l4 = lane >> 4;

  f32x4 acc[4][4];
  #pragma unroll
  for (int i = 0; i < 4; ++i)
    #pragma unroll
    for (int j = 0; j < 4; ++j)
      acc[i][j] = (f32x4){0.f, 0.f, 0.f, 0.f};

  const int nk = K >> 6;
  for (int kt = 0; kt < nk; ++kt){
    #pragma unroll
    for (int it = 0; it < 4; ++it){
      int ch = it*256 + tid;
      int r = ch >> 3, cc = ch & 7;
      int srcc = ((cc ^ (r & 7)) << 3);
      gload_lds16(A  + (row0 + r) * K + kt*64 + srcc, &As[ch*8]);
      gload_lds16(Bt + (long)(col0 + r) * K + kt*64 + srcc, &Bs[ch*8]);
    }
    __syncthreads();
    #pragma unroll
    for (int ks = 0; ks < 2; ++ks){
      short8 af[4], bfr[4];
      #pragma unroll
      for (int mi = 0; mi < 4; ++mi){
        int ar = wm*64 + mi*16 + l15;
        af[mi] = *(const short8*)&As[ar*64 + (((ks*4 + l4) ^ (ar & 7)) << 3)];
      }
      #pragma unroll
      for (int ni = 0; ni < 4; ++ni){
        int br = wn*64 + ni*16 + l15;
        bfr[ni] = *(const short8*)&Bs[br*64 + (((ks*4 + l4) ^ (br & 7)) << 3)];
      }
      #pragma unroll
      for (int mi = 0; mi < 4; ++mi)
        #pragma unroll
        for (int ni = 0; ni < 4; ++ni)
          acc[mi][ni] = __builtin_amdgcn_mfma_f32_16x16x32_bf16(bfr[ni], af[mi], acc[mi][ni], 0, 0, 0);
    }
    __syncthreads();
  }

  if (MODE == 2){
    float* outf = (float*)out;
    #pragma unroll
    for (int mi = 0; mi < 4; ++mi){
      long row = row0 + wm*64 + mi*16 + l15;
      #pragma unroll
      for (int ni = 0; ni < 4; ++ni){
        int colg = col0 + wn*64 + ni*16 + 4*l4;
        float4 bv = *(const float4*)&bias[colg];
        long idx = row * N + colg;
        ushort4 rv = *(const ushort4*)&res[idx];
        float4 o;
        o.x = acc[mi][ni][0] + bv.x + bf2f(rv.x);
        o.y = acc[mi][ni][1] + bv.y + bf2f(rv.y);
        o.z = acc[mi][ni][2] + bv.z + bf2f(rv.z);
        o.w = acc[mi][ni][3] + bv.w + bf2f(rv.w);
        *(float4*)&outf[idx] = o;
      }
    }
  } else {
    unsigned short* outp = (unsigned short*)out;
    #pragma unroll
    for (int mi = 0; mi < 4; ++mi){
      long row = row0 + wm*64 + mi*16 + l15;
      #pragma unroll
      for (int ni = 0; ni < 4; ++ni){
        int colg = col0 + wn*64 + ni*16 + 4*l4;
        float4 bv = *(const float4*)&bias[colg];
        float v0 = acc[mi][ni][0] + bv.x;
        float v1 = acc[mi][ni][1] + bv.y;
        float v2 = acc[mi][ni][2] + bv.z;
        float v3 = acc[mi][ni][3] + bv.w;
        if (MODE == 1){ v0 = gelu_f(v0); v1 = gelu_f(v1); v2 = gelu_f(v2); v3 = gelu_f(v3); }
        uint2 dv;
        dv.x = ((unsigned int)f2bf(v1) << 16) | f2bf(v0);
        dv.y = ((unsigned int)f2bf(v3) << 16) | f2bf(v2);
        *(uint2*)&outp[row * N + colg] = dv;
      }
    }
  }
}

// ---------------- Window attention: one WAVE = one (window, head) ------------
// Swapped QK^T and PV: packed uint2 P writes (16) and ao writes (8).
__global__ __launch_bounds__(64, 3) void attn_kernel(
    const unsigned short* __restrict__ qkv,
    const float* __restrict__ bt,
    unsigned short* __restrict__ ao){
  __shared__ unsigned short P[64*64];
  const int lane = threadIdx.x;
  const int wb = blockIdx.x;
  const int w = wb >> 3, h = wb & 7;
  const int bidx = w >> 10, rem = w & 1023;
  const int wy = rem >> 5, wx = rem & 31;
  const long tok0 = (long)bidx * 65536 + (long)wy * 2048 + wx * 8;
  const int l15 = lane & 15, l4 = lane >> 4;

  short8 qf[4], kf[4];
  #pragma unroll
  for (int t = 0; t < 4; ++t){
    int n = t*16 + l15;
    long tok = tok0 + (n >> 3) * 256 + (n & 7);
    qf[t] = *(const short8*)(qkv + tok*768 +       h*32 + 8*l4);
    kf[t] = *(const short8*)(qkv + tok*768 + 256 + h*32 + 8*l4);
  }
  // swapped: s[mi][ni]: lane holds q = mi*16+l15, k = ni*16+4*l4+{0..3}
  f32x4 s[4][4];
  #pragma unroll
  for (int i = 0; i < 4; ++i)
    #pragma unroll
    for (int j = 0; j < 4; ++j)
      s[i][j] = (f32x4){0.f, 0.f, 0.f, 0.f};
  #pragma unroll
  for (int mi = 0; mi < 4; ++mi)
    #pragma unroll
    for (int ni = 0; ni < 4; ++ni)
      s[mi][ni] = __builtin_amdgcn_mfma_f32_16x16x32_bf16(kf[ni], qf[mi], s[mi][ni], 0, 0, 0);

  const float scale = 0.17677669529663687f; // 1/sqrt(32)
  #pragma unroll
  for (int mi = 0; mi < 4; ++mi){
    int q = mi*16 + l15;
    int ny = q >> 3, nx = q & 7;
    // scale + relative-position bias
    #pragma unroll
    for (int ni = 0; ni < 4; ++ni){
      #pragma unroll
      for (int j = 0; j < 4; ++j){
        int k = ni*16 + 4*l4 + j;
        int db = (ny - (k >> 3) + 7) * 15 + (nx - (k & 7) + 7);
        s[mi][ni][j] = s[mi][ni][j] * scale + bt[db*8 + h];
      }
    }
    // softmax over k: 16 in-lane + across l4 groups (lanes share l15)
    float mx = -1e30f;
    #pragma unroll
    for (int ni = 0; ni < 4; ++ni)
      #pragma unroll
      for (int j = 0; j < 4; ++j)
        mx = fmaxf(mx, s[mi][ni][j]);
    mx = fmaxf(mx, __shfl_xor(mx, 16));
    mx = fmaxf(mx, __shfl_xor(mx, 32));
    float sm = 0.f;
    #pragma unroll
    for (int ni = 0; ni < 4; ++ni)
      #pragma unroll
      for (int j = 0; j < 4; ++j){
        float p = __expf(s[mi][ni][j] - mx);
        s[mi][ni][j] = p;
        sm += p;
      }
    sm += __shfl_xor(sm, 16);
    sm += __shfl_xor(sm, 32);
    float inv = __builtin_amdgcn_rcpf(sm);
    // packed P write: 4 consecutive k per lane
    #pragma unroll
    for (int ni = 0; ni < 4; ++ni){
      uint2 dv;
      dv.x = ((unsigned int)f2bf(s[mi][ni][1]*inv) << 16) | f2bf(s[mi][ni][0]*inv);
      dv.y = ((unsigned int)f2bf(s[mi][ni][3]*inv) << 16) | f2bf(s[mi][ni][2]*inv);
      int g = ni*2 + (l4 >> 1);
      *(uint2*)&P[q*64 + ((g ^ (q & 7)) << 3) + 4*(l4 & 1)] = dv;
    }
  }
  // single wave: no barrier needed (compiler orders via lgkmcnt)

  // PV swapped: o[mi][ni]: lane holds token = mi*16+l15, d = ni*16+4*l4+{0..3}
  f32x4 o[4][2];
  #pragma unroll
  for (int i = 0; i < 4; ++i)
    #pragma unroll
    for (int j = 0; j < 2; ++j)
      o[i][j] = (f32x4){0.f, 0.f, 0.f, 0.f};
  #pragma unroll
  for (int kt = 0; kt < 2; ++kt){
    short8 vf[2];
    #pragma unroll
    for (int ni = 0; ni < 2; ++ni){
      union { unsigned short u[8]; short8 v; } tmp;
      #pragma unroll
      for (int i = 0; i < 8; ++i){
        int kk = kt*32 + 8*l4 + i;
        long tok = tok0 + (kk >> 3) * 256 + (kk & 7);
        tmp.u[i] = qkv[tok*768 + 512 + h*32 + ni*16 + l15];
      }
      vf[ni] = tmp.v;
    }
    #pragma unroll
    for (int mi = 0; mi < 4; ++mi){
      int r = mi*16 + l15;
      short8 pf = *(const short8*)&P[r*64 + (((kt*4 + l4) ^ (r & 7)) << 3)];
      #pragma unroll
      for (int ni = 0; ni < 2; ++ni)
        o[mi][ni] = __builtin_amdgcn_mfma_f32_16x16x32_bf16(vf[ni], pf, o[mi][ni], 0, 0, 0);
    }
  }
  // packed ao write: 4 consecutive d per lane
  #pragma unroll
  for (int mi = 0; mi < 4; ++mi){
    int t = mi*16 + l15;
    long tok = tok0 + (t >> 3) * 256 + (t & 7);
    #pragma unroll
    for (int ni = 0; ni < 2; ++ni){
      uint2 dv;
      dv.x = ((unsigned int)f2bf(o[mi][ni][1]) << 16) | f2bf(o[mi][ni][0]);
      dv.y = ((unsigned int)f2bf(o[mi][ni][3]) << 16) | f2bf(o[mi][ni][2]);
      *(uint2*)&ao[tok*256 + h*32 + ni*16 + 4*l4] = dv;
    }
  }
}

// ---------------- proj + residual + LN2 fused (R13 version) ------------------
// writes h (bf16) and hn (bf16); LN2 stats computed on exact f32 values
__global__ __launch_bounds__(512, 4) void proj_ln2(
    const unsigned short* __restrict__ A,
    const unsigned short* __restrict__ Bt,
    const float* __restrict__ bias,
    const float* __restrict__ res,
    const float* __restrict__ g2,
    const float* __restrict__ b2,
    unsigned short* __restrict__ hout,
    unsigned short* __restrict__ hn){
  __shared__ unsigned short As[128*64];
  __shared__ unsigned short Bs[256*64];
  __shared__ float redsum[4][128];
  __shared__ float redsq[4][128];
  __shared__ float mu_s[128];
  __shared__ float rs_s[128];
  const int tid = threadIdx.x, lane = tid & 63, wave = tid >> 6;
  const int l15 = lane & 15, l4 = lane >> 4;
  const int wm = wave >> 2, wn = wave & 3;
  const long row0 = (long)blockIdx.x * 128;

  f32x4 acc[4][4];
  #pragma unroll
  for (int i = 0; i < 4; ++i)
    #pragma unroll
    for (int j = 0; j < 4; ++j)
      acc[i][j] = (f32x4){0.f, 0.f, 0.f, 0.f};

  for (int kt = 0; kt < 4; ++kt){
    #pragma unroll
    for (int it = 0; it < 2; ++it){
      int ch = it*512 + tid;
      int r = ch >> 3, cc = ch & 7;
      gload_lds16(A + (row0 + r)*256 + kt*64 + ((cc ^ (r & 7))*8), &As[ch*8]);
    }
    #pragma unroll
    for (int it = 0; it < 4; ++it){
      int ch = it*512 + tid;
      int r = ch >> 3, cc = ch & 7;
      gload_lds16(Bt + r*256 + kt*64 + ((cc ^ (r & 7))*8), &Bs[ch*8]);
    }
    __syncthreads();
    #pragma unroll
    for (int ks = 0; ks < 2; ++ks){
      short8 af[4], bf[4];
      #pragma unroll
      for (int mi = 0; mi < 4; ++mi){
        int ar = wm*64 + mi*16 + l15;
        af[mi] = *(const short8*)&As[ar*64 + (((ks*4 + l4) ^ (ar & 7))*8)];
      }
      #pragma unroll
      for (int ni = 0; ni < 4; ++ni){
        int br = wn*64 + ni*16 + l15;
        bf[ni] = *(const short8*)&Bs[br*64 + (((ks*4 + l4) ^ (br & 7))*8)];
      }
      #pragma unroll
      for (int mi = 0; mi < 4; ++mi)
        #pragma unroll
        for (int ni = 0; ni < 4; ++ni)
          acc[mi][ni] = __builtin_amdgcn_mfma_f32_16x16x32_bf16(af[mi], bf[ni], acc[mi][ni], 0, 0, 0);
    }
    __syncthreads();
  }

  float bcol[4];
  #pragma unroll
  for (int ni = 0; ni < 4; ++ni) bcol[ni] = bias[wn*64 + ni*16 + l15];
  f32x4 psum[4], psq[4];
  #pragma unroll
  for (int mi = 0; mi < 4; ++mi){
    psum[mi] = (f32x4){0.f,0.f,0.f,0.f};
    psq[mi]  = (f32x4){0.f,0.f,0.f,0.f};
    #pragma unroll
    for (int ni = 0; ni < 4; ++ni){
      int col = wn*64 + ni*16 + l15;
      #pragma unroll
      for (int j = 0; j < 4; ++j){
        long row = row0 + wm*64 + mi*16 + 4*l4 + j;
        long idx = row * 256 + col;
        float v = acc[mi][ni][j] + bcol[ni] + res[idx];
        hout[idx] = f2bf(v);
        acc[mi][ni][j] = v;
        psum[mi][j] += v;
        psq[mi][j]  += v * v;
      }
    }
  }
  #pragma unroll
  for (int mi = 0; mi < 4; ++mi){
    #pragma unroll
    for (int j = 0; j < 4; ++j){
      float s = psum[mi][j], q = psq[mi][j];
      #pragma unroll
      for (int m = 1; m < 16; m <<= 1){
        s += __shfl_xor(s, m);
        q += __shfl_xor(q, m);
      }
      if (l15 == 0){
        int rl = wm*64 + mi*16 + 4*l4 + j;
        redsum[wn][rl] = s;
        redsq[wn][rl]  = q;
      }
    }
  }
  __syncthreads();
  if (tid < 128){
    float s = redsum[0][tid] + redsum[1][tid] + redsum[2][tid] + redsum[3][tid];
    float q = redsq[0][tid]  + redsq[1][tid]  + redsq[2][tid]  + redsq[3][tid];
    float mu = s * (1.f/256.f);
    mu_s[tid] = mu;
    rs_s[tid] = rsqrtf(q * (1.f/256.f) - mu*mu + 1e-5f);
  }
  __syncthreads();
  float gcol[4], b2col[4];
  #pragma unroll
  for (int ni = 0; ni < 4; ++ni){
    gcol[ni]  = g2[wn*64 + ni*16 + l15];
    b2col[ni] = b2[wn*64 + ni*16 + l15];
  }
  #pragma unroll
  for (int mi = 0; mi < 4; ++mi){
    #pragma unroll
    for (int j = 0; j < 4; ++j){
      int rl = wm*64 + mi*16 + 4*l4 + j;
      float mu = mu_s[rl], rs = rs_s[rl];
      long row = row0 + rl;
      #pragma unroll
      for (int ni = 0; ni < 4; ++ni){
        int col = wn*64 + ni*16 + l15;
        hn[row*256 + col] = f2bf((acc[mi][ni][j] - mu)*rs*gcol[ni] + b2col[ni]);
      }
    }
  }
}

extern "C" void kernel_launch(void* const* d_in, const int* in_sizes, int n_in,
                              void* d_out, int out_size, void* d_ws, size_t ws_size,
                              hipStream_t stream){
  const float* x      = (const float*)d_in[0];
  const float* ln1_g  = (const float*)d_in[1];
  const float* ln1_b  = (const float*)d_in[2];
  const float* qkv_w  = (const float*)d_in[3];
  const float* qkv_b  = (const float*)d_in[4];
  const float* proj_w = (const float*)d_in[5];
  const float* proj_b = (const float*)d_in[6];
  const float* btab   = (const float*)d_in[7];
  const float* ln2_g  = (const float*)d_in[8];
  const float* ln2_b  = (const float*)d_in[9];
  const float* fc1_w  = (const float*)d_in[10];
  const float* fc1_b  = (const float*)d_in[11];
  const float* fc2_w  = (const float*)d_in[12];
  const float* fc2_b  = (const float*)d_in[13];

  const long M = (long)in_sizes[0] / 256;  // 262144 tokens

  char* ws = (char*)d_ws;
  unsigned short* xn  = (unsigned short*)(ws);
  unsigned short* ao  = xn;
  unsigned short* act = xn;
  unsigned short* qkv = (unsigned short*)(ws + 134217728);
  unsigned short* hn  = (unsigned short*)(ws + 536870912);
  unsigned short* wq  = (unsigned short*)(ws + 671088640);
  unsigned short* wp  = wq + 256*768;
  unsigned short* w1  = wp + 256*256;
  unsigned short* w2  = w1 + 256*1024;
  unsigned short* hh  = (unsigned short*)(ws + (712ull << 20));
  float* outf = (float*)d_out;

  // all 4 weight transposes in one launch (786432 elems)
  wconv4<<<3072, 256, 0, stream>>>(qkv_w, proj_w, fc1_w, fc2_w, wq, wp, w1, w2);

  // LN1
  ln_kernel<<<M/4, 256, 0, stream>>>(x, ln1_g, ln1_b, xn);
  // QKV (swizzled): nbx=6
  gemm_bt<0><<<6 * (M/128), 256, 0, stream>>>(xn, wq, qkv_b, nullptr, qkv, 768, 256, 6);
  // window attention: one wave per (window, head)
  attn_kernel<<<(M/64) * 8, 64, 0, stream>>>(qkv, btab, ao);
  // proj + residual + LN2  (h bf16 -> hh, hn bf16)
  proj_ln2<<<M/128, 512, 0, stream>>>(ao, wp, proj_b, x, ln2_g, ln2_b, hh, hn);
  // FC1 + GELU (swizzled): nbx=8
  gemm_bt<1><<<8 * (M/128), 256, 0, stream>>>(hn, w1, fc1_b, nullptr, act, 1024, 256, 8);
  // FC2 + residual(h bf16) -> out f32 (swizzled): nbx=2
  gemm_bt<2><<<2 * (M/128), 256, 0, stream>>>(act, w2, fc2_b, hh, outf, 256, 1024, 2);
}